// Round 8
// baseline (473.495 us; speedup 1.0000x reference)
//
#include <hip/hip_runtime.h>

#define FFT_N   4096
#define THREADS 512

__device__ __forceinline__ float2 cmul(float2 w, float2 v) {
    return make_float2(fmaf(w.x, v.x, -w.y * v.y), fmaf(w.x, v.y, w.y * v.x));
}
__device__ __forceinline__ float2 cmni(float2 v) { return make_float2(v.y, -v.x); }
__device__ __forceinline__ void bfly(float2& a, float2& b, float2 w) {
    float2 t = cmul(w, b);
    b = make_float2(a.x - t.x, a.y - t.y);
    a = make_float2(a.x + t.x, a.y + t.y);
}
// XOR-fold swizzle (verified round 2).
__device__ __forceinline__ int swz(int i) { return i ^ ((i >> 4) & 15) ^ ((i >> 8) & 15); }

// lgkmcnt-only barrier: global loads/stores stay in flight across it.
__device__ __forceinline__ void bar() {
    asm volatile("s_waitcnt lgkmcnt(0)" ::: "memory");
    __builtin_amdgcn_s_barrier();
}
__device__ __forceinline__ void radix8(float2 u[8], float2 A, float2 B, float2 C, float2 D) {
    bfly(u[0], u[1], A); bfly(u[2], u[3], A); bfly(u[4], u[5], A); bfly(u[6], u[7], A);
    float2 Bn = cmni(B);
    bfly(u[0], u[2], B); bfly(u[1], u[3], Bn); bfly(u[4], u[6], B); bfly(u[5], u[7], Bn);
    float2 Cn = cmni(C), Dn = cmni(D);
    bfly(u[0], u[4], C); bfly(u[1], u[5], D); bfly(u[2], u[6], Cn); bfly(u[3], u[7], Dn);
}

struct Row { float2 u[8]; };

__device__ __forceinline__ void load_row(Row& r, const float* __restrict__ xr,
                                         const float* __restrict__ xi, int t) {
    const int off[8] = {0, 2048, 1024, 3072, 512, 2560, 1536, 3584};
#pragma unroll
    for (int j = 0; j < 8; ++j) r.u[j] = make_float2(xr[t + off[j]], xi[t + off[j]]);
}

// Prefetch half a row (4 complex = 8 dwords), pinned so loads can't sink.
template <int J0>
__device__ __forceinline__ void issue4(Row& n, const float* __restrict__ xr,
                                       const float* __restrict__ xi, int t, bool en) {
    const int off[8] = {0, 2048, 1024, 3072, 512, 2560, 1536, 3584};
    if (en) {
#pragma unroll
        for (int j = J0; j < J0 + 4; ++j) n.u[j] = make_float2(xr[t + off[j]], xi[t + off[j]]);
    }
    asm volatile("" ::: "memory");
}

// Deferred store of half the previous row's results (4 complex = 8 dwords), pinned.
template <int J0>
__device__ __forceinline__ void store4(const Row& p, float* __restrict__ yr,
                                       float* __restrict__ yi, int t, bool en) {
    if (en) {
#pragma unroll
        for (int j = J0; j < J0 + 4; ++j) { yr[t + 512 * j] = p.u[j].x; yi[t + 512 * j] = p.u[j].y; }
    }
    asm volatile("" ::: "memory");
}

// One row through 4 passes. W = this row's data (in) -> this row's results (out, kept
// in registers as pending). O = prev row's pending results (stored in P0/P1), then
// reused as the prefetch target for the next row (loaded in P2/P3).
// Uniform VMEM issue: 8 dwords per phase (stores P0/P1, loads P2/P3).
__device__ __forceinline__ void process_row(Row& W, Row& O, float2* lds, int t,
        float2 C1, float2 C2, float2 C3,
        float* __restrict__ pyr, float* __restrict__ pyi, bool pst,
        const float* __restrict__ nxr, const float* __restrict__ nxi, bool more)
{
    const float2 one  = make_float2(1.f, 0.f);
    const float2 w512 = make_float2(0.70710678118654752f, -0.70710678118654752f);

    // ---- P0 (stages 0..2): twiddles 1,1,1,W512. Pend stores lo half.
    store4<0>(O, pyr, pyi, t, pst);
    radix8(W.u, one, one, one, w512);
    const int g0 = (int)(__brev((unsigned)t) >> 23);   // rev9(t)
#pragma unroll
    for (int j = 0; j < 8; ++j) lds[swz(8 * g0 + j)] = W.u[j];
    bar();

    // ---- P1 (stages 3..5). Pend stores hi half; O is dead afterwards.
    store4<4>(O, pyr, pyi, t, pst);
    const int b1 = (t & 7) | (((t >> 4) & 1) << 6) | (((t >> 3) & 1) << 7) | ((t >> 5) << 8);
#pragma unroll
    for (int j = 0; j < 8; ++j) W.u[j] = lds[swz(b1 + 8 * j)];
    { float2 B = cmul(C1, C1), A = cmul(B, B), D = cmul(C1, w512);
      radix8(W.u, A, B, C1, D); }
#pragma unroll
    for (int j = 0; j < 8; ++j) lds[swz(b1 + 8 * j)] = W.u[j];   // same slots: no pre-barrier
    bar();

    // ---- P2 (stages 6..8). Prefetch next row lo half into O.
    issue4<0>(O, nxr, nxi, t, more);
    const int b2 = (t & 63) | ((t >> 6) << 9);
#pragma unroll
    for (int j = 0; j < 8; ++j) W.u[j] = lds[swz(b2 + 64 * j)];
    { float2 B = cmul(C2, C2), A = cmul(B, B), D = cmul(C2, w512);
      radix8(W.u, A, B, C2, D); }
#pragma unroll
    for (int j = 0; j < 8; ++j) lds[swz(b2 + 64 * j)] = W.u[j];
    bar();

    // ---- P3 (stages 9..11). Prefetch next row hi half. Results STAY in W.u (pending).
    issue4<4>(O, nxr, nxi, t, more);
#pragma unroll
    for (int j = 0; j < 8; ++j) W.u[j] = lds[swz(t + 512 * j)];
    { float2 B = cmul(C3, C3), A = cmul(B, B), D = cmul(C3, w512);
      radix8(W.u, A, B, C3, D); }
    bar();   // P3 reads done before next row's P0 scatter reuses LDS
}

__global__ __launch_bounds__(THREADS, 8) void fft4096_dstore_kernel(
    const float* __restrict__ x_re, const float* __restrict__ x_im,
    const float* __restrict__ W_re, const float* __restrict__ W_im,
    float* __restrict__ out, int batch, int rows_per)
{
    __shared__ float2 lds[FFT_N];
    const int t = threadIdx.x;

    const float2 C1 = make_float2(W_re[(t & 7) << 6],  W_im[(t & 7) << 6]);
    const float2 C2 = make_float2(W_re[(t & 63) << 3], W_im[(t & 63) << 3]);
    const float2 C3 = make_float2(W_re[t],             W_im[t]);

    const int row0 = blockIdx.x * rows_per;
    float* out_im = out + (size_t)batch * FFT_N;
    Row X, Y;

    if (rows_per & 1) {   // generic fallback (not hit for batch=8192)
        for (int i = 0; i < rows_per; ++i) {
            const int r = row0 + i;
            load_row(X, x_re + (size_t)r * FFT_N, x_im + (size_t)r * FFT_N, t);
            asm volatile("" ::: "memory");
            process_row(X, Y, lds, t, C1, C2, C3,
                        out, out_im, false, x_re, x_im, false);
            float* yr = out + (size_t)r * FFT_N;
            float* yi = out_im + (size_t)r * FFT_N;
#pragma unroll
            for (int j = 0; j < 8; ++j) { yr[t + 512 * j] = X.u[j].x; yi[t + 512 * j] = X.u[j].y; }
        }
        return;
    }

    load_row(X, x_re + (size_t)row0 * FFT_N, x_im + (size_t)row0 * FFT_N, t);
    asm volatile("" ::: "memory");

    for (int i = 0; i < rows_per; i += 2) {
        const int r0 = row0 + i, r1 = r0 + 1;
        const bool m1 = (i + 2) < rows_per;
        const int r2 = m1 ? (r0 + 2) : row0;             // clamped; loads gated by m1
        const int rp = (i > 0) ? (r0 - 1) : r0;          // clamped; stores gated by pst

        // row r0: work=X; Y = pend(r0-1) then prefetch(r1)
        process_row(X, Y, lds, t, C1, C2, C3,
                    out + (size_t)rp * FFT_N, out_im + (size_t)rp * FFT_N, i > 0,
                    x_re + (size_t)r1 * FFT_N, x_im + (size_t)r1 * FFT_N, true);
        // X = r0 results (pending); Y = r1 data
        process_row(Y, X, lds, t, C1, C2, C3,
                    out + (size_t)r0 * FFT_N, out_im + (size_t)r0 * FFT_N, true,
                    x_re + (size_t)r2 * FFT_N, x_im + (size_t)r2 * FFT_N, m1);
        // Y = r1 results (pending); X = r2 data (if m1)
    }

    // Flush: Y holds the last row's results.
    {
        const int rl = row0 + rows_per - 1;
        float* yr = out + (size_t)rl * FFT_N;
        float* yi = out_im + (size_t)rl * FFT_N;
#pragma unroll
        for (int j = 0; j < 8; ++j) { yr[t + 512 * j] = Y.u[j].x; yi[t + 512 * j] = Y.u[j].y; }
    }
}

extern "C" void kernel_launch(void* const* d_in, const int* in_sizes, int n_in,
                              void* d_out, int out_size, void* d_ws, size_t ws_size,
                              hipStream_t stream) {
    const float* x_re = (const float*)d_in[0];
    const float* x_im = (const float*)d_in[1];
    const float* W_re = (const float*)d_in[2];
    const float* W_im = (const float*)d_in[3];
    // d_in[4] = bitrev (unused: bit-reversal folded into the pass-0 load pattern)
    const int batch = in_sizes[0] / FFT_N;
    float* out = (float*)d_out;

    int rows_per = 8;
    while (rows_per > 1 && (batch % rows_per)) rows_per >>= 1;
    const int grid = batch / rows_per;
    fft4096_dstore_kernel<<<grid, THREADS, 0, stream>>>(x_re, x_im, W_re, W_im, out, batch, rows_per);
}

// Round 10
// 123.626 us; speedup vs baseline: 3.8301x; 3.8301x over previous
//
#include <hip/hip_runtime.h>

#define FFT_N   4096
#define THREADS 256

__device__ __forceinline__ float2 cmul(float2 w, float2 v) {
    return make_float2(fmaf(w.x, v.x, -w.y * v.y), fmaf(w.x, v.y, w.y * v.x));
}
__device__ __forceinline__ float2 cmni(float2 v) { return make_float2(v.y, -v.x); }
__device__ __forceinline__ void bfly(float2& a, float2& b, float2 w) {
    float2 t = cmul(w, b);
    b = make_float2(a.x - t.x, a.y - t.y);
    a = make_float2(a.x + t.x, a.y + t.y);
}
__device__ __forceinline__ void bfly1(float2& a, float2& b) {   // tw = 1
    float2 t = b;
    b = make_float2(a.x - t.x, a.y - t.y);
    a = make_float2(a.x + t.x, a.y + t.y);
}
__device__ __forceinline__ void bflyni(float2& a, float2& b) {  // tw = -i
    float2 t = make_float2(b.y, -b.x);
    b = make_float2(a.x - t.x, a.y - t.y);
    a = make_float2(a.x + t.x, a.y + t.y);
}
// XOR-fold swizzle (verified rounds 2-8; radix-16 patterns are rank-4 linear
// lane->bank-pair maps under the same fold).
__device__ __forceinline__ int swz(int i) { return i ^ ((i >> 4) & 15) ^ ((i >> 8) & 15); }
// lgkmcnt-only barrier: global loads/stores stay in flight across it.
__device__ __forceinline__ void bar() {
    asm volatile("s_waitcnt lgkmcnt(0)" ::: "memory");
    __builtin_amdgcn_s_barrier();
}

#define Q1x  0.70710678118654752f      // cos(pi/4)
#define Q3x -0.70710678118654752f
// 16th roots (CORRECTED r10: r9 had half-angle/32nd-root constants here):
// e^{-i pi/8} and e^{-i 3pi/8}
#define E1x 0.923879532511286756f      // cos(pi/8)
#define E1y -0.382683432365089772f     // -sin(pi/8)
#define E3x 0.382683432365089772f      // cos(3pi/8)
#define E3y -0.923879532511286756f     // -sin(3pi/8)

// Radix-16 = 4 radix-2 stages on u[j] = element (base + j*s); group phase r,
// G = W[r*N/(16s)] chain hoisted by caller: G2=G^2, G4=G^4, G8=G^8.
__device__ __forceinline__ void radix16(float2 u[16], float2 G, float2 G2, float2 G4, float2 G8) {
    // stage a (j-stride 1): tw = G8
#pragma unroll
    for (int m = 0; m < 16; m += 2) bfly(u[m], u[m + 1], G8);
    // stage b (j-stride 2): tw = G4 * {1,-i}[j&1]
    float2 G4n = cmni(G4);
#pragma unroll
    for (int b = 0; b < 16; b += 4) { bfly(u[b], u[b + 2], G4); bfly(u[b + 1], u[b + 3], G4n); }
    // stage c (j-stride 4): tw = G2 * {1, e^-ipi/4, -i, e^-i3pi/4}[j&3]
    float2 t1 = cmul(G2, make_float2(Q1x, -Q1x));
    float2 t2 = cmni(G2);
    float2 t3 = cmul(G2, make_float2(Q3x, -Q1x));
#pragma unroll
    for (int b = 0; b < 16; b += 8) {
        bfly(u[b + 0], u[b + 4], G2); bfly(u[b + 1], u[b + 5], t1);
        bfly(u[b + 2], u[b + 6], t2); bfly(u[b + 3], u[b + 7], t3);
    }
    // stage d (j-stride 8): tw = G * e^{-i pi j/8}, j=0..7; upper half = -i * lower half
    float2 s1 = cmul(G, make_float2(E1x, E1y));
    float2 s2 = cmul(G, make_float2(Q1x, -Q1x));
    float2 s3 = cmul(G, make_float2(E3x, E3y));
    float2 s4 = cmni(G);
    float2 s5 = cmni(s1);
    float2 s6 = cmni(s2);
    float2 s7 = cmni(s3);
    bfly(u[0], u[8],  G);  bfly(u[1], u[9],  s1);
    bfly(u[2], u[10], s2); bfly(u[3], u[11], s3);
    bfly(u[4], u[12], s4); bfly(u[5], u[13], s5);
    bfly(u[6], u[14], s6); bfly(u[7], u[15], s7);
}

// Pass A: all twiddles are compile-time constants (G = 1).
__device__ __forceinline__ void radix16_first(float2 u[16]) {
#pragma unroll
    for (int m = 0; m < 16; m += 2) bfly1(u[m], u[m + 1]);
#pragma unroll
    for (int b = 0; b < 16; b += 4) { bfly1(u[b], u[b + 2]); bflyni(u[b + 1], u[b + 3]); }
#pragma unroll
    for (int b = 0; b < 16; b += 8) {
        bfly1(u[b + 0], u[b + 4]);
        bfly(u[b + 1], u[b + 5], make_float2(Q1x, -Q1x));
        bflyni(u[b + 2], u[b + 6]);
        bfly(u[b + 3], u[b + 7], make_float2(Q3x, -Q1x));
    }
    // stage d: tw = e^{-i pi j/8}
    bfly1(u[0], u[8]);
    bfly(u[1], u[9],  make_float2(E1x, E1y));
    bfly(u[2], u[10], make_float2(Q1x, -Q1x));
    bfly(u[3], u[11], make_float2(E3x, E3y));
    bflyni(u[4], u[12]);
    bfly(u[5], u[13], make_float2(E1y, -E1x));   // -i * e^{-i pi/8}
    bfly(u[6], u[14], make_float2(Q3x, -Q1x));   // e^{-i 3pi/4}
    bfly(u[7], u[15], make_float2(E3y, -E3x));   // -i * e^{-i 3pi/8}
}

__global__ __launch_bounds__(THREADS) void fft4096_r16_kernel(
    const float* __restrict__ x_re, const float* __restrict__ x_im,
    const float* __restrict__ W_re, const float* __restrict__ W_im,
    float* __restrict__ out, int batch, int rows_per)
{
    __shared__ float2 lds[FFT_N];
    const int t = threadIdx.x;

    // Row-invariant twiddle chains (hoisted out of the row loop).
    const int rB = t & 15;
    const float2 GB  = make_float2(W_re[rB << 4], W_im[rB << 4]);
    const float2 GB2 = cmul(GB, GB);
    const float2 GB4 = cmul(GB2, GB2);
    const float2 GB8 = cmul(GB4, GB4);
    const float2 GC  = make_float2(W_re[t], W_im[t]);
    const float2 GC2 = cmul(GC, GC);
    const float2 GC4 = cmul(GC2, GC2);
    const float2 GC8 = cmul(GC4, GC4);

    const int g  = (int)(__brev((unsigned)t) >> 24);      // rev8(t)
    const int bB = (t & 15) | ((t >> 4) << 8);            // pass-B group base
    const int row0 = blockIdx.x * rows_per;
    float* out_im = out + (size_t)batch * FFT_N;

    for (int i = 0; i < rows_per; ++i) {
        const int r = row0 + i;
        const float* xr = x_re + (size_t)r * FFT_N;
        const float* xi = x_im + (size_t)r * FFT_N;
        float2 u[16];

        // Coalesced bit-reversed load: u[j] = x[t + 256*rev4(j)].
        const int off[16] = {0, 2048, 1024, 3072, 512, 2560, 1536, 3584,
                             256, 2304, 1280, 3328, 768, 2816, 1792, 3840};
#pragma unroll
        for (int j = 0; j < 16; ++j) u[j] = make_float2(xr[t + off[j]], xi[t + off[j]]);

        // ---- pass A (stages 0..3): constant twiddles; scatter 16g+j.
        radix16_first(u);
#pragma unroll
        for (int j = 0; j < 16; ++j) lds[swz(16 * g + j)] = u[j];
        bar();

        // ---- pass B (stages 4..7): groups {bB + 16j}, in-place (same slots).
#pragma unroll
        for (int j = 0; j < 16; ++j) u[j] = lds[swz(bB + 16 * j)];
        radix16(u, GB, GB2, GB4, GB8);
#pragma unroll
        for (int j = 0; j < 16; ++j) lds[swz(bB + 16 * j)] = u[j];
        bar();

        // ---- pass C (stages 8..11): groups {t + 256j}; results -> global directly.
#pragma unroll
        for (int j = 0; j < 16; ++j) u[j] = lds[swz(t + 256 * j)];
        radix16(u, GC, GC2, GC4, GC8);
        float* yr = out + (size_t)r * FFT_N;
        float* yi = out_im + (size_t)r * FFT_N;
#pragma unroll
        for (int j = 0; j < 16; ++j) { yr[t + 256 * j] = u[j].x; yi[t + 256 * j] = u[j].y; }
        bar();   // pass-C reads done before next row's pass-A scatter reuses LDS
    }
}

extern "C" void kernel_launch(void* const* d_in, const int* in_sizes, int n_in,
                              void* d_out, int out_size, void* d_ws, size_t ws_size,
                              hipStream_t stream) {
    const float* x_re = (const float*)d_in[0];
    const float* x_im = (const float*)d_in[1];
    const float* W_re = (const float*)d_in[2];
    const float* W_im = (const float*)d_in[3];
    // d_in[4] = bitrev (unused: bit-reversal folded into the pass-A load pattern)
    const int batch = in_sizes[0] / FFT_N;
    float* out = (float*)d_out;

    int rows_per = 8;
    while (rows_per > 1 && (batch % rows_per)) rows_per >>= 1;
    const int grid = batch / rows_per;
    fft4096_r16_kernel<<<grid, THREADS, 0, stream>>>(x_re, x_im, W_re, W_im, out, batch, rows_per);
}

// Round 11
// 117.951 us; speedup vs baseline: 4.0144x; 1.0481x over previous
//
#include <hip/hip_runtime.h>

#define FFT_N   4096
#define THREADS 256

__device__ __forceinline__ float2 cmul(float2 w, float2 v) {
    return make_float2(fmaf(w.x, v.x, -w.y * v.y), fmaf(w.x, v.y, w.y * v.x));
}
__device__ __forceinline__ float2 cmni(float2 v) { return make_float2(v.y, -v.x); }
__device__ __forceinline__ void bfly(float2& a, float2& b, float2 w) {
    float2 t = cmul(w, b);
    b = make_float2(a.x - t.x, a.y - t.y);
    a = make_float2(a.x + t.x, a.y + t.y);
}
__device__ __forceinline__ void bfly1(float2& a, float2& b) {   // tw = 1
    float2 t = b;
    b = make_float2(a.x - t.x, a.y - t.y);
    a = make_float2(a.x + t.x, a.y + t.y);
}
__device__ __forceinline__ void bflyni(float2& a, float2& b) {  // tw = -i
    float2 t = make_float2(b.y, -b.x);
    b = make_float2(a.x - t.x, a.y - t.y);
    a = make_float2(a.x + t.x, a.y + t.y);
}
// XOR-fold swizzle (verified rounds 2-10).
__device__ __forceinline__ int swz(int i) { return i ^ ((i >> 4) & 15) ^ ((i >> 8) & 15); }
// lgkmcnt-only barrier: global loads/stores stay in flight across it.
__device__ __forceinline__ void bar() {
    asm volatile("s_waitcnt lgkmcnt(0)" ::: "memory");
    __builtin_amdgcn_s_barrier();
}

#define Q1x  0.70710678118654752f      // cos(pi/4)
#define Q3x -0.70710678118654752f
// 16th roots: e^{-i pi/8}, e^{-i 3pi/8}  (r10-corrected constants)
#define E1x 0.923879532511286756f
#define E1y -0.382683432365089772f
#define E3x 0.382683432365089772f
#define E3y -0.923879532511286756f

// Radix-16 = 4 radix-2 stages on u[j]; G chain hoisted by caller.
__device__ __forceinline__ void radix16(float2 u[16], float2 G, float2 G2, float2 G4, float2 G8) {
#pragma unroll
    for (int m = 0; m < 16; m += 2) bfly(u[m], u[m + 1], G8);
    float2 G4n = cmni(G4);
#pragma unroll
    for (int b = 0; b < 16; b += 4) { bfly(u[b], u[b + 2], G4); bfly(u[b + 1], u[b + 3], G4n); }
    float2 t1 = cmul(G2, make_float2(Q1x, -Q1x));
    float2 t2 = cmni(G2);
    float2 t3 = cmul(G2, make_float2(Q3x, -Q1x));
#pragma unroll
    for (int b = 0; b < 16; b += 8) {
        bfly(u[b + 0], u[b + 4], G2); bfly(u[b + 1], u[b + 5], t1);
        bfly(u[b + 2], u[b + 6], t2); bfly(u[b + 3], u[b + 7], t3);
    }
    float2 s1 = cmul(G, make_float2(E1x, E1y));
    float2 s2 = cmul(G, make_float2(Q1x, -Q1x));
    float2 s3 = cmul(G, make_float2(E3x, E3y));
    float2 s4 = cmni(G);
    float2 s5 = cmni(s1);
    float2 s6 = cmni(s2);
    float2 s7 = cmni(s3);
    bfly(u[0], u[8],  G);  bfly(u[1], u[9],  s1);
    bfly(u[2], u[10], s2); bfly(u[3], u[11], s3);
    bfly(u[4], u[12], s4); bfly(u[5], u[13], s5);
    bfly(u[6], u[14], s6); bfly(u[7], u[15], s7);
}

// Pass A: all twiddles compile-time constants (G = 1).
__device__ __forceinline__ void radix16_first(float2 u[16]) {
#pragma unroll
    for (int m = 0; m < 16; m += 2) bfly1(u[m], u[m + 1]);
#pragma unroll
    for (int b = 0; b < 16; b += 4) { bfly1(u[b], u[b + 2]); bflyni(u[b + 1], u[b + 3]); }
#pragma unroll
    for (int b = 0; b < 16; b += 8) {
        bfly1(u[b + 0], u[b + 4]);
        bfly(u[b + 1], u[b + 5], make_float2(Q1x, -Q1x));
        bflyni(u[b + 2], u[b + 6]);
        bfly(u[b + 3], u[b + 7], make_float2(Q3x, -Q1x));
    }
    bfly1(u[0], u[8]);
    bfly(u[1], u[9],  make_float2(E1x, E1y));
    bfly(u[2], u[10], make_float2(Q1x, -Q1x));
    bfly(u[3], u[11], make_float2(E3x, E3y));
    bflyni(u[4], u[12]);
    bfly(u[5], u[13], make_float2(E1y, -E1x));   // -i * e^{-i pi/8}
    bfly(u[6], u[14], make_float2(Q3x, -Q1x));   // e^{-i 3pi/4}
    bfly(u[7], u[15], make_float2(E3y, -E3x));   // -i * e^{-i 3pi/8}
}

struct Row { float2 u[16]; };

__device__ __constant__ const int koff[16] = {0, 2048, 1024, 3072, 512, 2560, 1536, 3584,
                                              256, 2304, 1280, 3328, 768, 2816, 1792, 3840};

// Full-row load (prologue only): u[j] = x[t + 256*rev4(j)], coalesced.
__device__ __forceinline__ void load_row(Row& r, const float* __restrict__ xr,
                                         const float* __restrict__ xi, int t) {
#pragma unroll
    for (int j = 0; j < 16; ++j) r.u[j] = make_float2(xr[t + koff[j]], xi[t + koff[j]]);
}

// Pinned prefetch chunk: CNT complex loads, then a memory clobber so the
// compiler cannot sink them to the use site (r6-verified mechanism).
template <int J0, int CNT>
__device__ __forceinline__ void issueN(Row& n, const float* __restrict__ xr,
                                       const float* __restrict__ xi, int t, bool en) {
    if (en) {
#pragma unroll
        for (int j = J0; j < J0 + CNT; ++j) n.u[j] = make_float2(xr[t + koff[j]], xi[t + koff[j]]);
    }
    asm volatile("" ::: "memory");
}

// One row through 3 radix-16 passes; next row's 16 loads issued 6/5/5 across
// the passes (pinned), so each chunk has >=1 full pass of latency cover.
__device__ __forceinline__ void process_row(Row& W, Row& P, float2* lds, int t,
        float2 GB, float2 GB2, float2 GB4, float2 GB8,
        float2 GC, float2 GC2, float2 GC4, float2 GC8,
        int g, int bB,
        float* __restrict__ yr, float* __restrict__ yi,
        const float* __restrict__ nxr, const float* __restrict__ nxi, bool more)
{
    // ---- pass A (stages 0..3): constant twiddles; scatter 16g+j.
    issueN<0, 6>(P, nxr, nxi, t, more);
    radix16_first(W.u);
#pragma unroll
    for (int j = 0; j < 16; ++j) lds[swz(16 * g + j)] = W.u[j];
    bar();

    // ---- pass B (stages 4..7): groups {bB + 16j}, in-place slots.
    issueN<6, 5>(P, nxr, nxi, t, more);
#pragma unroll
    for (int j = 0; j < 16; ++j) W.u[j] = lds[swz(bB + 16 * j)];
    radix16(W.u, GB, GB2, GB4, GB8);
#pragma unroll
    for (int j = 0; j < 16; ++j) lds[swz(bB + 16 * j)] = W.u[j];
    bar();

    // ---- pass C (stages 8..11): groups {t + 256j}; results -> global directly.
    issueN<11, 5>(P, nxr, nxi, t, more);
#pragma unroll
    for (int j = 0; j < 16; ++j) W.u[j] = lds[swz(t + 256 * j)];
    radix16(W.u, GC, GC2, GC4, GC8);
#pragma unroll
    for (int j = 0; j < 16; ++j) { yr[t + 256 * j] = W.u[j].x; yi[t + 256 * j] = W.u[j].y; }
    bar();   // pass-C reads done before next row's pass-A scatter reuses LDS
}

__global__ __launch_bounds__(THREADS) void fft4096_r16p_kernel(
    const float* __restrict__ x_re, const float* __restrict__ x_im,
    const float* __restrict__ W_re, const float* __restrict__ W_im,
    float* __restrict__ out, int batch, int rows_per)
{
    __shared__ float2 lds[FFT_N];
    const int t = threadIdx.x;

    // Row-invariant twiddle chains (hoisted).
    const int rB = t & 15;
    const float2 GB  = make_float2(W_re[rB << 4], W_im[rB << 4]);
    const float2 GB2 = cmul(GB, GB);
    const float2 GB4 = cmul(GB2, GB2);
    const float2 GB8 = cmul(GB4, GB4);
    const float2 GC  = make_float2(W_re[t], W_im[t]);
    const float2 GC2 = cmul(GC, GC);
    const float2 GC4 = cmul(GC2, GC2);
    const float2 GC8 = cmul(GC4, GC4);

    const int g  = (int)(__brev((unsigned)t) >> 24);      // rev8(t)
    const int bB = (t & 15) | ((t >> 4) << 8);            // pass-B group base
    const int row0 = blockIdx.x * rows_per;
    float* out_im = out + (size_t)batch * FFT_N;
    Row X, Y;

    if (rows_per & 1) {   // generic fallback (not hit for batch=8192)
        for (int i = 0; i < rows_per; ++i) {
            const int r = row0 + i;
            load_row(X, x_re + (size_t)r * FFT_N, x_im + (size_t)r * FFT_N, t);
            asm volatile("" ::: "memory");
            process_row(X, Y, lds, t, GB, GB2, GB4, GB8, GC, GC2, GC4, GC8, g, bB,
                        out + (size_t)r * FFT_N, out_im + (size_t)r * FFT_N,
                        x_re, x_im, false);
        }
        return;
    }

    load_row(X, x_re + (size_t)row0 * FFT_N, x_im + (size_t)row0 * FFT_N, t);
    asm volatile("" ::: "memory");

    for (int i = 0; i < rows_per; i += 2) {
        const int r0 = row0 + i, r1 = r0 + 1;
        const bool m1 = (i + 2) < rows_per;
        const int r2 = m1 ? (r0 + 2) : row0;             // clamped; loads gated by m1

        // row r0: work = X, prefetch r1 into Y
        process_row(X, Y, lds, t, GB, GB2, GB4, GB8, GC, GC2, GC4, GC8, g, bB,
                    out + (size_t)r0 * FFT_N, out_im + (size_t)r0 * FFT_N,
                    x_re + (size_t)r1 * FFT_N, x_im + (size_t)r1 * FFT_N, true);
        // row r1: work = Y, prefetch r2 into X
        process_row(Y, X, lds, t, GB, GB2, GB4, GB8, GC, GC2, GC4, GC8, g, bB,
                    out + (size_t)r1 * FFT_N, out_im + (size_t)r1 * FFT_N,
                    x_re + (size_t)r2 * FFT_N, x_im + (size_t)r2 * FFT_N, m1);
    }
}

extern "C" void kernel_launch(void* const* d_in, const int* in_sizes, int n_in,
                              void* d_out, int out_size, void* d_ws, size_t ws_size,
                              hipStream_t stream) {
    const float* x_re = (const float*)d_in[0];
    const float* x_im = (const float*)d_in[1];
    const float* W_re = (const float*)d_in[2];
    const float* W_im = (const float*)d_in[3];
    // d_in[4] = bitrev (unused: bit-reversal folded into the pass-A load pattern)
    const int batch = in_sizes[0] / FFT_N;
    float* out = (float*)d_out;

    int rows_per = 8;
    while (rows_per > 1 && (batch % rows_per)) rows_per >>= 1;
    const int grid = batch / rows_per;
    fft4096_r16p_kernel<<<grid, THREADS, 0, stream>>>(x_re, x_im, W_re, W_im, out, batch, rows_per);
}

// Round 12
// 114.812 us; speedup vs baseline: 4.1241x; 1.0273x over previous
//
#include <hip/hip_runtime.h>

#define FFT_N   4096
#define THREADS 512

__device__ __forceinline__ float2 cmul(float2 w, float2 v) {
    return make_float2(fmaf(w.x, v.x, -w.y * v.y), fmaf(w.x, v.y, w.y * v.x));
}
__device__ __forceinline__ float2 cmni(float2 v) { return make_float2(v.y, -v.x); }
__device__ __forceinline__ void bfly(float2& a, float2& b, float2 w) {
    float2 t = cmul(w, b);
    b = make_float2(a.x - t.x, a.y - t.y);
    a = make_float2(a.x + t.x, a.y + t.y);
}
// XOR-fold swizzle (verified round 2: conflicts 1.7e7 -> ~1e6).
__device__ __forceinline__ int swz(int i) { return i ^ ((i >> 4) & 15) ^ ((i >> 8) & 15); }

// lgkmcnt-only barrier: prefetched global loads stay in flight (no vmcnt drain).
__device__ __forceinline__ void bar() {
    asm volatile("s_waitcnt lgkmcnt(0)" ::: "memory");
    __builtin_amdgcn_s_barrier();
}
// radix-8 = 3 radix-2 stages on u[j] = element (base + j*s).
__device__ __forceinline__ void radix8(float2 u[8], float2 A, float2 B, float2 C, float2 D) {
    bfly(u[0], u[1], A); bfly(u[2], u[3], A); bfly(u[4], u[5], A); bfly(u[6], u[7], A);
    float2 Bn = cmni(B);
    bfly(u[0], u[2], B); bfly(u[1], u[3], Bn); bfly(u[4], u[6], B); bfly(u[5], u[7], Bn);
    float2 Cn = cmni(C), Dn = cmni(D);
    bfly(u[0], u[4], C); bfly(u[1], u[5], D); bfly(u[2], u[6], Cn); bfly(u[3], u[7], Dn);
}

struct Row { float2 u[8]; };

// Bit-reversed coalesced pattern: u[j] = x[t + 512*rev3(j)].
__device__ __forceinline__ void load_row(Row& r, const float* __restrict__ xr,
                                         const float* __restrict__ xi, int t) {
    const int off[8] = {0, 2048, 1024, 3072, 512, 2560, 1536, 3584};
#pragma unroll
    for (int j = 0; j < 8; ++j) r.u[j] = make_float2(xr[t + off[j]], xi[t + off[j]]);
}

// Issue 2 complex prefetch loads (4 dwords), then PIN them with a memory
// clobber so the compiler cannot sink them to the use site (round-5 lesson:
// VGPR==data-size proves the prefetch was being sunk).
__device__ __forceinline__ void issue2(Row& n, int a, int b, int offa, int offb,
                                       const float* __restrict__ xr,
                                       const float* __restrict__ xi, int t, bool en) {
    if (en) {
        n.u[a] = make_float2(xr[t + offa], xi[t + offa]);
        n.u[b] = make_float2(xr[t + offb], xi[t + offb]);
    }
    asm volatile("" ::: "memory");
}

// 4 radix-8 passes; next row's 16 loads issued 4-per-phase (right after each
// barrier) so HBM request arrival is smooth and each chunk has >=1 phase of
// latency cover before consumption.
__device__ __forceinline__ void process_row(Row& r, float2* lds, int t,
        float2 C1, float2 C2, float2 C3, float2 w512,
        float* __restrict__ yr, float* __restrict__ yi,
        Row& nxt, const float* __restrict__ nxr, const float* __restrict__ nxi, bool en)
{
    const float2 one = make_float2(1.f, 0.f);

    // ---- pass 0 (stages 0..2): twiddles 1,1,1,W512.
    issue2(nxt, 0, 1, 0, 2048, nxr, nxi, t, en);
    radix8(r.u, one, one, one, w512);
    const int g0 = (int)(__brev((unsigned)t) >> 23);   // rev9(t)
#pragma unroll
    for (int j = 0; j < 8; ++j) lds[swz(8 * g0 + j)] = r.u[j];
    bar();

    // ---- pass 1 (stages 3..5)
    issue2(nxt, 2, 3, 1024, 3072, nxr, nxi, t, en);
    const int b1 = (t & 7) | (((t >> 4) & 1) << 6) | (((t >> 3) & 1) << 7) | ((t >> 5) << 8);
#pragma unroll
    for (int j = 0; j < 8; ++j) r.u[j] = lds[swz(b1 + 8 * j)];
    { float2 B = cmul(C1, C1), A = cmul(B, B), D = cmul(C1, w512);
      radix8(r.u, A, B, C1, D); }
#pragma unroll
    for (int j = 0; j < 8; ++j) lds[swz(b1 + 8 * j)] = r.u[j];   // same slots: no pre-barrier
    bar();

    // ---- pass 2 (stages 6..8)
    issue2(nxt, 4, 5, 512, 2560, nxr, nxi, t, en);
    const int b2 = (t & 63) | ((t >> 6) << 9);
#pragma unroll
    for (int j = 0; j < 8; ++j) r.u[j] = lds[swz(b2 + 64 * j)];
    { float2 B = cmul(C2, C2), A = cmul(B, B), D = cmul(C2, w512);
      radix8(r.u, A, B, C2, D); }
#pragma unroll
    for (int j = 0; j < 8; ++j) lds[swz(b2 + 64 * j)] = r.u[j];
    bar();

    // ---- pass 3 (stages 9..11): thread t ends holding y[t + 512j].
    issue2(nxt, 6, 7, 1536, 3584, nxr, nxi, t, en);
#pragma unroll
    for (int j = 0; j < 8; ++j) r.u[j] = lds[swz(t + 512 * j)];
    { float2 B = cmul(C3, C3), A = cmul(B, B), D = cmul(C3, w512);
      radix8(r.u, A, B, C3, D); }
#pragma unroll
    for (int j = 0; j < 8; ++j) { yr[t + 512 * j] = r.u[j].x; yi[t + 512 * j] = r.u[j].y; }
    bar();   // pass-3 reads done before next row's pass-0 scatter reuses LDS
}

__global__ __launch_bounds__(THREADS) void fft4096_pin_kernel(
    const float* __restrict__ x_re, const float* __restrict__ x_im,
    const float* __restrict__ W_re, const float* __restrict__ W_im,
    float* __restrict__ out, int batch, int rows_per)
{
    __shared__ float2 lds[FFT_N];
    const int t = threadIdx.x;

    // Row-invariant twiddle bases (B=C^2, A=B^2, D=C*W512 derived per pass).
    const float2 C1 = make_float2(W_re[(t & 7) << 6],  W_im[(t & 7) << 6]);
    const float2 C2 = make_float2(W_re[(t & 63) << 3], W_im[(t & 63) << 3]);
    const float2 C3 = make_float2(W_re[t],             W_im[t]);
    const float2 w512 = make_float2(0.70710678118654752f, -0.70710678118654752f);

    const int row0 = blockIdx.x * rows_per;
    Row A, B;

    if (rows_per & 1) {   // generic fallback (not hit for batch=8192)
        for (int i = 0; i < rows_per; ++i) {
            const int r = row0 + i;
            load_row(A, x_re + (size_t)r * FFT_N, x_im + (size_t)r * FFT_N, t);
            asm volatile("" ::: "memory");
            process_row(A, lds, t, C1, C2, C3, w512,
                        out + (size_t)r * FFT_N, out + ((size_t)batch + r) * FFT_N,
                        B, x_re, x_im, false);
        }
        return;
    }

    load_row(A, x_re + (size_t)row0 * FFT_N, x_im + (size_t)row0 * FFT_N, t);
    asm volatile("" ::: "memory");
    for (int i = 0; i < rows_per; i += 2) {
        const int r0 = row0 + i, r1 = r0 + 1;
        const bool en2 = (i + 2) < rows_per;
        const int r2 = en2 ? (r0 + 2) : row0;   // clamped ptr; loads gated by en2
        process_row(A, lds, t, C1, C2, C3, w512,
                    out + (size_t)r0 * FFT_N, out + ((size_t)batch + r0) * FFT_N,
                    B, x_re + (size_t)r1 * FFT_N, x_im + (size_t)r1 * FFT_N, true);
        process_row(B, lds, t, C1, C2, C3, w512,
                    out + (size_t)r1 * FFT_N, out + ((size_t)batch + r1) * FFT_N,
                    A, x_re + (size_t)r2 * FFT_N, x_im + (size_t)r2 * FFT_N, en2);
    }
}

extern "C" void kernel_launch(void* const* d_in, const int* in_sizes, int n_in,
                              void* d_out, int out_size, void* d_ws, size_t ws_size,
                              hipStream_t stream) {
    const float* x_re = (const float*)d_in[0];
    const float* x_im = (const float*)d_in[1];
    const float* W_re = (const float*)d_in[2];
    const float* W_im = (const float*)d_in[3];
    // d_in[4] = bitrev (unused: bit-reversal folded into the pass-0 load pattern)
    const int batch = in_sizes[0] / FFT_N;
    float* out = (float*)d_out;

    int rows_per = 8;
    while (rows_per > 1 && (batch % rows_per)) rows_per >>= 1;
    const int grid = batch / rows_per;
    fft4096_pin_kernel<<<grid, THREADS, 0, stream>>>(x_re, x_im, W_re, W_im, out, batch, rows_per);
}